// Round 2
// baseline (1070.589 us; speedup 1.0000x reference)
//
#include <hip/hip_runtime.h>
#include <hip/hip_bf16.h>
#include <math.h>

#define M_SLOTS 8192
#define N_DIM   4096
#define FVS     64
#define PLEN    64
#define CDIM    256
#define NIN     512
#define NOUT    512
#define STEPS   8
#define EPS_F   1e-8f

// ---------------- helpers ----------------

__device__ inline float wave_sum(float v) {
    for (int off = 32; off; off >>= 1) v += __shfl_down(v, off);
    return v;
}

// block(1024) sum: all threads receive the result. sh must have >=17 floats.
__device__ inline float blk_sum_1024(float v, float* sh) {
    v = wave_sum(v);
    int lane = threadIdx.x & 63, wid = threadIdx.x >> 6;
    if (lane == 0) sh[wid] = v;
    __syncthreads();
    if (threadIdx.x < 16) {
        v = sh[threadIdx.x];
        for (int off = 8; off; off >>= 1) v += __shfl_down(v, off);
        if (threadIdx.x == 0) sh[16] = v;
    }
    __syncthreads();
    float r = sh[16];
    __syncthreads();
    return r;
}

__device__ inline float blk_max_1024(float v, float* sh) {
    for (int off = 32; off; off >>= 1) v = fmaxf(v, __shfl_down(v, off));
    int lane = threadIdx.x & 63, wid = threadIdx.x >> 6;
    if (lane == 0) sh[wid] = v;
    __syncthreads();
    if (threadIdx.x < 16) {
        v = sh[threadIdx.x];
        for (int off = 8; off; off >>= 1) v = fmaxf(v, __shfl_down(v, off));
        if (threadIdx.x == 0) sh[16] = v;
    }
    __syncthreads();
    float r = sh[16];
    __syncthreads();
    return r;
}

// ---------------- kernels ----------------

// X = x @ input_embedding, then c = sigmoid(Wc @ concat(X, prog0) + bc)
__global__ void k_init_ctrl(const float* __restrict__ x, const float* __restrict__ emb,
                            const float* __restrict__ prog0,
                            const float* __restrict__ Wc, const float* __restrict__ bc,
                            float* __restrict__ X, float* __restrict__ c) {
    __shared__ float in[FVS + PLEN];
    int tid = threadIdx.x;  // 256
    if (tid < FVS) {
        float acc = 0.f;
        for (int i = 0; i < NIN; ++i) acc += x[i] * emb[i * FVS + tid];
        X[tid] = acc;
        in[tid] = acc;
    } else if (tid < FVS + PLEN) {
        in[tid] = prog0[tid - FVS];
    }
    __syncthreads();
    float acc = bc[tid];
    const float* wrow = Wc + tid * (FVS + PLEN);
    #pragma unroll 8
    for (int i = 0; i < FVS + PLEN; ++i) acc += wrow[i] * in[i];
    c[tid] = 1.f / (1.f + expf(-acc));
}

// k = tanh(Wk@c+bk), e = sigmoid(We@c+be), a = tanh(Wa@c+ba), kr = tanh(Wrk@prog+brk)
__global__ void k_keys(const float* __restrict__ c, const float* __restrict__ prog_t,
                       const float* __restrict__ Wk, const float* __restrict__ bk,
                       const float* __restrict__ We, const float* __restrict__ be,
                       const float* __restrict__ Wa, const float* __restrict__ ba,
                       const float* __restrict__ Wrk, const float* __restrict__ brk,
                       float* __restrict__ k, float* __restrict__ e,
                       float* __restrict__ a, float* __restrict__ kr) {
    int gw   = (blockIdx.x * blockDim.x + threadIdx.x) >> 6;
    int lane = threadIdx.x & 63;
    int mat  = gw >> 12;
    int row  = gw & 4095;
    float acc = 0.f;
    if (mat == 0) {
        const float* W = Wk + row * CDIM;
        #pragma unroll
        for (int i = lane; i < CDIM; i += 64) acc += W[i] * c[i];
    } else if (mat == 1) {
        const float* W = We + row * CDIM;
        #pragma unroll
        for (int i = lane; i < CDIM; i += 64) acc += W[i] * c[i];
    } else if (mat == 2) {
        const float* W = Wa + row * CDIM;
        #pragma unroll
        for (int i = lane; i < CDIM; i += 64) acc += W[i] * c[i];
    } else {
        acc = Wrk[row * PLEN + lane] * prog_t[lane];
    }
    acc = wave_sum(acc);
    if (lane == 0) {
        if (mat == 0)      k[row]  = tanhf(acc + bk[row]);
        else if (mat == 1) e[row]  = 1.f / (1.f + expf(-(acc + be[row])));
        else if (mat == 2) a[row]  = tanhf(acc + ba[row]);
        else               kr[row] = tanhf(acc + brk[row]);
    }
}

// One pass over mem_old computing 8 row-reductions:
// s0=mem.k  s1=mem.kr  s2=mem.(e*kr)  s3=mem.a  s4=mem.(e*a)
// s5=|mem|^2  s6=mem^2.e  s7=mem^2.e^2
#define SIM_THREADS 512
#define SIM_ROWS    16
__global__ __launch_bounds__(SIM_THREADS) void k_sim8(
        const float* __restrict__ mem,
        const float* __restrict__ k, const float* __restrict__ kr,
        const float* __restrict__ a, const float* __restrict__ e,
        float* __restrict__ simk, float* __restrict__ n2old,
        float* __restrict__ skr, float* __restrict__ sekr,
        float* __restrict__ sa, float* __restrict__ sea,
        float* __restrict__ qe, float* __restrict__ qe2) {
    __shared__ float K[N_DIM], KR[N_DIM], A[N_DIM], E[N_DIM];
    __shared__ float sh[8][8];
    int tid = threadIdx.x;
    for (int i = tid; i < N_DIM / 4; i += SIM_THREADS) {
        ((float4*)K)[i]  = ((const float4*)k)[i];
        ((float4*)KR)[i] = ((const float4*)kr)[i];
        ((float4*)A)[i]  = ((const float4*)a)[i];
        ((float4*)E)[i]  = ((const float4*)e)[i];
    }
    __syncthreads();
    int r0 = blockIdx.x * SIM_ROWS;
    for (int rr = 0; rr < SIM_ROWS; ++rr) {
        int m = r0 + rr;
        const float4* row = (const float4*)(mem + (size_t)m * N_DIM);
        float s0=0,s1=0,s2=0,s3=0,s4=0,s5=0,s6=0,s7=0;
        #pragma unroll
        for (int ii = 0; ii < N_DIM / 4 / SIM_THREADS; ++ii) {
            int i = tid + ii * SIM_THREADS;
            float4 v  = row[i];
            float4 kk = ((float4*)K)[i];
            float4 rr4= ((float4*)KR)[i];
            float4 aa = ((float4*)A)[i];
            float4 ee = ((float4*)E)[i];
            #define ACC1(c) { float vv=v.c, kv=kk.c, rv=rr4.c, av=aa.c, ev=ee.c; \
                s0 += vv*kv; s1 += vv*rv; s2 += vv*ev*rv; s3 += vv*av; s4 += vv*ev*av; \
                float v2 = vv*vv; s5 += v2; s6 += v2*ev; s7 += v2*ev*ev; }
            ACC1(x) ACC1(y) ACC1(z) ACC1(w)
            #undef ACC1
        }
        s0 = wave_sum(s0); s1 = wave_sum(s1); s2 = wave_sum(s2); s3 = wave_sum(s3);
        s4 = wave_sum(s4); s5 = wave_sum(s5); s6 = wave_sum(s6); s7 = wave_sum(s7);
        int lane = tid & 63, wid = tid >> 6;
        if (lane == 0) {
            sh[wid][0]=s0; sh[wid][1]=s1; sh[wid][2]=s2; sh[wid][3]=s3;
            sh[wid][4]=s4; sh[wid][5]=s5; sh[wid][6]=s6; sh[wid][7]=s7;
        }
        __syncthreads();
        if (tid < 8) {
            float tot = sh[0][tid]+sh[1][tid]+sh[2][tid]+sh[3][tid]
                      + sh[4][tid]+sh[5][tid]+sh[6][tid]+sh[7][tid];
            switch (tid) {
                case 0: simk[m]  = tot; break;
                case 1: skr[m]   = tot; break;
                case 2: sekr[m]  = tot; break;
                case 3: sa[m]    = tot; break;
                case 4: sea[m]   = tot; break;
                case 5: n2old[m] = tot; break;
                case 6: qe[m]    = tot; break;
                case 7: qe2[m]   = tot; break;
            }
        }
        __syncthreads();
    }
}

// Both addressings in one block: write softmax -> ww, then analytic
// sim_new/norm2_new -> read softmax -> wr.
__global__ __launch_bounds__(1024) void k_addr(
        const float* __restrict__ k, const float* __restrict__ kr, const float* __restrict__ a,
        const float* __restrict__ simk, const float* __restrict__ n2old,
        const float* __restrict__ skr, const float* __restrict__ sekr,
        const float* __restrict__ sa, const float* __restrict__ sea,
        const float* __restrict__ qe, const float* __restrict__ qe2,
        float* __restrict__ ww, float* __restrict__ wr) {
    __shared__ float sh[17];
    int tid = threadIdx.x;
    float d0=0,d1=0,d2=0,d3=0;
    for (int i = tid; i < N_DIM; i += 1024) {
        float kv = k[i], krv = kr[i], av = a[i];
        d0 += kv*kv; d1 += krv*krv; d2 += av*krv; d3 += av*av;
    }
    d0 = blk_sum_1024(d0, sh);
    d1 = blk_sum_1024(d1, sh);
    d2 = blk_sum_1024(d2, sh);
    d3 = blk_sum_1024(d3, sh);
    float knorm = sqrtf(d0), krnorm = sqrtf(d1);

    // write addressing softmax
    float v[M_SLOTS / 1024];
    float mx = -INFINITY;
    #pragma unroll
    for (int j = 0; j < M_SLOTS / 1024; ++j) {
        int m = tid + j * 1024;
        v[j] = simk[m] / (sqrtf(n2old[m]) * knorm + EPS_F);
        mx = fmaxf(mx, v[j]);
    }
    mx = blk_max_1024(mx, sh);
    float ls = 0.f;
    #pragma unroll
    for (int j = 0; j < M_SLOTS / 1024; ++j) { v[j] = expf(v[j] - mx); ls += v[j]; }
    ls = blk_sum_1024(ls, sh);
    float inv = 1.f / ls;
    float wv[M_SLOTS / 1024];
    #pragma unroll
    for (int j = 0; j < M_SLOTS / 1024; ++j) {
        wv[j] = v[j] * inv;
        ww[tid + j * 1024] = wv[j];
    }

    // analytic sim/norm on updated memory, then read softmax
    float mx2 = -INFINITY;
    #pragma unroll
    for (int j = 0; j < M_SLOTS / 1024; ++j) {
        int m = tid + j * 1024;
        float w1 = wv[j];
        float sim2 = skr[m] - w1 * sekr[m] + w1 * d2;
        float n2 = n2old[m] - 2.f*w1*qe[m] + w1*w1*qe2[m]
                 + 2.f*w1*sa[m] - 2.f*w1*w1*sea[m] + w1*w1*d3;
        v[j] = sim2 / (sqrtf(n2) * krnorm + EPS_F);
        mx2 = fmaxf(mx2, v[j]);
    }
    mx2 = blk_max_1024(mx2, sh);
    float ls2 = 0.f;
    #pragma unroll
    for (int j = 0; j < M_SLOTS / 1024; ++j) { v[j] = expf(v[j] - mx2); ls2 += v[j]; }
    ls2 = blk_sum_1024(ls2, sh);
    float inv2 = 1.f / ls2;
    #pragma unroll
    for (int j = 0; j < M_SLOTS / 1024; ++j) wr[tid + j * 1024] = v[j] * inv2;
}

// Fused: mem_new = mem_old*(1-ww*e) + ww*a ; partial[rc] += wr*mem_new
// grid (4, 128) x 256 threads; thread owns one float4 column, loops 64 rows.
__global__ void k_update_read(const float* __restrict__ src, float* __restrict__ dst,
                              const float* __restrict__ ww, const float* __restrict__ wr,
                              const float* __restrict__ e, const float* __restrict__ a,
                              float* __restrict__ partial) {
    int c4 = blockIdx.x * 256 + threadIdx.x;   // [0, 1024)
    int rc = blockIdx.y;                       // [0, 128)
    int r0 = rc * 64;
    const float4* s4 = (const float4*)src;
    float4*       d4 = (float4*)dst;
    float4 ee = ((const float4*)e)[c4];
    float4 aa = ((const float4*)a)[c4];
    float4 acc = make_float4(0.f, 0.f, 0.f, 0.f);
    for (int r = r0; r < r0 + 64; ++r) {
        float w1 = ww[r], w2 = wr[r];
        float4 v = s4[(size_t)r * (N_DIM / 4) + c4];
        float4 nv;
        nv.x = v.x * (1.f - w1 * ee.x) + w1 * aa.x;
        nv.y = v.y * (1.f - w1 * ee.y) + w1 * aa.y;
        nv.z = v.z * (1.f - w1 * ee.z) + w1 * aa.z;
        nv.w = v.w * (1.f - w1 * ee.w) + w1 * aa.w;
        d4[(size_t)r * (N_DIM / 4) + c4] = nv;
        acc.x += w2 * nv.x; acc.y += w2 * nv.y; acc.z += w2 * nv.z; acc.w += w2 * nv.w;
    }
    ((float4*)partial)[(size_t)rc * (N_DIM / 4) + c4] = acc;
}

// red[c] = sum_j partial[j][c]   (16 blocks x 256)
__global__ void k_read_reduce(const float* __restrict__ partial, float* __restrict__ red) {
    int cidx = blockIdx.x * 256 + threadIdx.x;
    float acc = 0.f;
    #pragma unroll 8
    for (int j = 0; j < 128; ++j) acc += partial[j * N_DIM + cidx];
    red[cidx] = acc;
}

// X = tanh(X @ red.reshape(64,64)); optionally c = sigmoid(Wc@concat(X,prog)+bc)
__global__ void k_exec_ctrl(float* __restrict__ X, const float* __restrict__ red,
                            const float* __restrict__ prog_next,
                            const float* __restrict__ Wc, const float* __restrict__ bc,
                            float* __restrict__ c, int do_ctrl) {
    __shared__ float in[FVS + PLEN];
    __shared__ float xs[FVS];
    int tid = threadIdx.x;  // 256
    if (tid < FVS) xs[tid] = X[tid];
    __syncthreads();
    if (tid < FVS) {
        float acc = 0.f;
        #pragma unroll
        for (int i = 0; i < FVS; ++i) acc += xs[i] * red[i * FVS + tid];
        float xn = tanhf(acc);
        X[tid] = xn;
        in[tid] = xn;
    } else if (do_ctrl && tid < FVS + PLEN) {
        in[tid] = prog_next[tid - FVS];
    }
    __syncthreads();
    if (do_ctrl) {
        float acc = bc[tid];
        const float* wrow = Wc + tid * (FVS + PLEN);
        #pragma unroll 8
        for (int i = 0; i < FVS + PLEN; ++i) acc += wrow[i] * in[i];
        c[tid] = 1.f / (1.f + expf(-acc));
    }
}

// out = X @ output_embedding   (1x64 @ 64x512)
__global__ void k_out(const float* __restrict__ X, const float* __restrict__ emb,
                      float* __restrict__ out) {
    __shared__ float xs[FVS];
    int tid = threadIdx.x;  // 512
    if (tid < FVS) xs[tid] = X[tid];
    __syncthreads();
    float acc = 0.f;
    #pragma unroll
    for (int i = 0; i < FVS; ++i) acc += xs[i] * emb[i * NOUT + tid];
    out[tid] = acc;
}

// ---------------- launch ----------------

extern "C" void kernel_launch(void* const* d_in, const int* in_sizes, int n_in,
                              void* d_out, int out_size, void* d_ws, size_t ws_size,
                              hipStream_t stream) {
    const float* x        = (const float*)d_in[0];
    const float* program  = (const float*)d_in[1];
    const float* memory0  = (const float*)d_in[2];
    const float* in_emb   = (const float*)d_in[3];
    const float* out_emb  = (const float*)d_in[4];
    const float* Wc       = (const float*)d_in[5];
    const float* bc       = (const float*)d_in[6];
    const float* Wk       = (const float*)d_in[7];
    const float* bk       = (const float*)d_in[8];
    const float* We       = (const float*)d_in[9];
    const float* be       = (const float*)d_in[10];
    const float* Wa       = (const float*)d_in[11];
    const float* ba       = (const float*)d_in[12];
    const float* Wrk      = (const float*)d_in[13];
    const float* brk      = (const float*)d_in[14];
    float* out = (float*)d_out;

    float* wsmem   = (float*)d_ws;                        // [M_SLOTS * N_DIM]
    float* partial = wsmem + (size_t)M_SLOTS * N_DIM;     // [128 * N_DIM]
    float* X       = partial + 128 * N_DIM;
    float* c       = X + FVS;
    float* kv      = c + CDIM;
    float* ev      = kv + N_DIM;
    float* av      = ev + N_DIM;
    float* krv     = av + N_DIM;
    float* simk    = krv + N_DIM;
    float* n2old   = simk + M_SLOTS;
    float* skr     = n2old + M_SLOTS;
    float* sekr    = skr + M_SLOTS;
    float* sa      = sekr + M_SLOTS;
    float* sea     = sa + M_SLOTS;
    float* qe      = sea + M_SLOTS;
    float* qe2     = qe + M_SLOTS;
    float* ww      = qe2 + M_SLOTS;
    float* wr      = ww + M_SLOTS;
    float* red     = wr + M_SLOTS;

    k_init_ctrl<<<1, 256, 0, stream>>>(x, in_emb, program, Wc, bc, X, c);

    for (int t = 0; t < STEPS; ++t) {
        const float* prog_t = program + t * PLEN;
        const float* src    = (t == 0) ? memory0 : wsmem;

        k_keys<<<4096, 256, 0, stream>>>(c, prog_t, Wk, bk, We, be, Wa, ba, Wrk, brk,
                                         kv, ev, av, krv);
        k_sim8<<<M_SLOTS / SIM_ROWS, SIM_THREADS, 0, stream>>>(
            src, kv, krv, av, ev, simk, n2old, skr, sekr, sa, sea, qe, qe2);
        k_addr<<<1, 1024, 0, stream>>>(kv, krv, av, simk, n2old, skr, sekr, sa, sea,
                                       qe, qe2, ww, wr);
        k_update_read<<<dim3(4, 128), 256, 0, stream>>>(src, wsmem, ww, wr, ev, av, partial);
        k_read_reduce<<<16, 256, 0, stream>>>(partial, red);
        k_exec_ctrl<<<1, 256, 0, stream>>>(X, red,
                                           (t < STEPS - 1) ? program + (t + 1) * PLEN : nullptr,
                                           Wc, bc, c, (t < STEPS - 1) ? 1 : 0);
    }

    k_out<<<1, NOUT, 0, stream>>>(X, out_emb, out);
}

// Round 3
// 1002.541 us; speedup vs baseline: 1.0679x; 1.0679x over previous
//
#include <hip/hip_runtime.h>
#include <hip/hip_bf16.h>
#include <math.h>

#define M_SLOTS 8192
#define N_DIM   4096
#define FVS     64
#define PLEN    64
#define CDIM    256
#define NIN     512
#define NOUT    512
#define STEPS   8
#define EPS_F   1e-8f

#define RCHUNK  16                      // rows per update_read y-block
#define NCHUNKS (M_SLOTS / RCHUNK)      // 512

// ---------------- helpers ----------------

__device__ inline float wave_sum(float v) {
    for (int off = 32; off; off >>= 1) v += __shfl_down(v, off);
    return v;
}

__device__ inline float blk_sum_1024(float v, float* sh) {
    v = wave_sum(v);
    int lane = threadIdx.x & 63, wid = threadIdx.x >> 6;
    if (lane == 0) sh[wid] = v;
    __syncthreads();
    if (threadIdx.x < 16) {
        v = sh[threadIdx.x];
        for (int off = 8; off; off >>= 1) v += __shfl_down(v, off);
        if (threadIdx.x == 0) sh[16] = v;
    }
    __syncthreads();
    float r = sh[16];
    __syncthreads();
    return r;
}

__device__ inline float blk_max_1024(float v, float* sh) {
    for (int off = 32; off; off >>= 1) v = fmaxf(v, __shfl_down(v, off));
    int lane = threadIdx.x & 63, wid = threadIdx.x >> 6;
    if (lane == 0) sh[wid] = v;
    __syncthreads();
    if (threadIdx.x < 16) {
        v = sh[threadIdx.x];
        for (int off = 8; off; off >>= 1) v = fmaxf(v, __shfl_down(v, off));
        if (threadIdx.x == 0) sh[16] = v;
    }
    __syncthreads();
    float r = sh[16];
    __syncthreads();
    return r;
}

// ---------------- kernels ----------------

// X = x @ input_embedding, then c = sigmoid(Wc @ concat(X, prog0) + bc)
__global__ void k_init_ctrl(const float* __restrict__ x, const float* __restrict__ emb,
                            const float* __restrict__ prog0,
                            const float* __restrict__ Wc, const float* __restrict__ bc,
                            float* __restrict__ X, float* __restrict__ c) {
    __shared__ float in[FVS + PLEN];
    int tid = threadIdx.x;  // 256
    if (tid < FVS) {
        float acc = 0.f;
        for (int i = 0; i < NIN; ++i) acc += x[i] * emb[i * FVS + tid];
        X[tid] = acc;
        in[tid] = acc;
    } else if (tid < FVS + PLEN) {
        in[tid] = prog0[tid - FVS];
    }
    __syncthreads();
    float acc = bc[tid];
    const float* wrow = Wc + tid * (FVS + PLEN);
    #pragma unroll 8
    for (int i = 0; i < FVS + PLEN; ++i) acc += wrow[i] * in[i];
    c[tid] = 1.f / (1.f + expf(-acc));
}

// k = tanh(Wk@c+bk), e = sigmoid(We@c+be), a = tanh(Wa@c+ba), kr = tanh(Wrk@prog+brk)
__global__ void k_keys(const float* __restrict__ c, const float* __restrict__ prog_t,
                       const float* __restrict__ Wk, const float* __restrict__ bk,
                       const float* __restrict__ We, const float* __restrict__ be,
                       const float* __restrict__ Wa, const float* __restrict__ ba,
                       const float* __restrict__ Wrk, const float* __restrict__ brk,
                       float* __restrict__ k, float* __restrict__ e,
                       float* __restrict__ a, float* __restrict__ kr) {
    int gw   = (blockIdx.x * blockDim.x + threadIdx.x) >> 6;
    int lane = threadIdx.x & 63;
    int mat  = gw >> 12;
    int row  = gw & 4095;
    float acc = 0.f;
    if (mat == 0) {
        const float* W = Wk + row * CDIM;
        #pragma unroll
        for (int i = lane; i < CDIM; i += 64) acc += W[i] * c[i];
    } else if (mat == 1) {
        const float* W = We + row * CDIM;
        #pragma unroll
        for (int i = lane; i < CDIM; i += 64) acc += W[i] * c[i];
    } else if (mat == 2) {
        const float* W = Wa + row * CDIM;
        #pragma unroll
        for (int i = lane; i < CDIM; i += 64) acc += W[i] * c[i];
    } else {
        acc = Wrk[row * PLEN + lane] * prog_t[lane];
    }
    acc = wave_sum(acc);
    if (lane == 0) {
        if (mat == 0)      k[row]  = tanhf(acc + bk[row]);
        else if (mat == 1) e[row]  = 1.f / (1.f + expf(-(acc + be[row])));
        else if (mat == 2) a[row]  = tanhf(acc + ba[row]);
        else               kr[row] = tanhf(acc + brk[row]);
    }
}

// One streaming pass over mem computing 8 row-reductions, one block per row:
// s0=mem.k s1=mem.kr s2=mem.(e*kr) s3=mem.a s4=mem.(e*a) s5=|mem|^2 s6=mem^2.e s7=mem^2.e^2
__global__ __launch_bounds__(256) void k_sim8(
        const float* __restrict__ mem,
        const float* __restrict__ k, const float* __restrict__ kr,
        const float* __restrict__ a, const float* __restrict__ e,
        float* __restrict__ simk, float* __restrict__ n2old,
        float* __restrict__ skr, float* __restrict__ sekr,
        float* __restrict__ sa, float* __restrict__ sea,
        float* __restrict__ qe, float* __restrict__ qe2) {
    int m = blockIdx.x;
    int tid = threadIdx.x;
    const float4* row = (const float4*)(mem + (size_t)m * N_DIM);
    const float4* K4  = (const float4*)k;
    const float4* R4  = (const float4*)kr;
    const float4* A4  = (const float4*)a;
    const float4* E4  = (const float4*)e;
    float s0=0,s1=0,s2=0,s3=0,s4=0,s5=0,s6=0,s7=0;
    #pragma unroll
    for (int ii = 0; ii < N_DIM / 4 / 256; ++ii) {   // 4 iters
        int i = tid + ii * 256;
        float4 v  = row[i];
        float4 kk = K4[i];
        float4 rr = R4[i];
        float4 aa = A4[i];
        float4 ee = E4[i];
        #define ACC1(c) { float vv=v.c, kv=kk.c, rv=rr.c, av=aa.c, ev=ee.c; \
            float ve = vv*ev; float v2 = vv*vv; \
            s0 += vv*kv; s1 += vv*rv; s2 += ve*rv; s3 += vv*av; s4 += ve*av; \
            s5 += v2; s6 += v2*ev; s7 += v2*(ev*ev); }
        ACC1(x) ACC1(y) ACC1(z) ACC1(w)
        #undef ACC1
    }
    s0 = wave_sum(s0); s1 = wave_sum(s1); s2 = wave_sum(s2); s3 = wave_sum(s3);
    s4 = wave_sum(s4); s5 = wave_sum(s5); s6 = wave_sum(s6); s7 = wave_sum(s7);
    __shared__ float sh[4][8];
    int lane = tid & 63, wid = tid >> 6;
    if (lane == 0) {
        sh[wid][0]=s0; sh[wid][1]=s1; sh[wid][2]=s2; sh[wid][3]=s3;
        sh[wid][4]=s4; sh[wid][5]=s5; sh[wid][6]=s6; sh[wid][7]=s7;
    }
    __syncthreads();
    if (tid < 8) {
        float tot = sh[0][tid] + sh[1][tid] + sh[2][tid] + sh[3][tid];
        switch (tid) {
            case 0: simk[m]  = tot; break;
            case 1: skr[m]   = tot; break;
            case 2: sekr[m]  = tot; break;
            case 3: sa[m]    = tot; break;
            case 4: sea[m]   = tot; break;
            case 5: n2old[m] = tot; break;
            case 6: qe[m]    = tot; break;
            case 7: qe2[m]   = tot; break;
        }
    }
}

// Both addressings in one block: write softmax -> ww, then analytic
// sim_new/norm2_new -> read softmax -> wr.
__global__ __launch_bounds__(1024) void k_addr(
        const float* __restrict__ k, const float* __restrict__ kr, const float* __restrict__ a,
        const float* __restrict__ simk, const float* __restrict__ n2old,
        const float* __restrict__ skr, const float* __restrict__ sekr,
        const float* __restrict__ sa, const float* __restrict__ sea,
        const float* __restrict__ qe, const float* __restrict__ qe2,
        float* __restrict__ ww, float* __restrict__ wr) {
    __shared__ float sh[17];
    int tid = threadIdx.x;
    float d0=0,d1=0,d2=0,d3=0;
    for (int i = tid; i < N_DIM; i += 1024) {
        float kv = k[i], krv = kr[i], av = a[i];
        d0 += kv*kv; d1 += krv*krv; d2 += av*krv; d3 += av*av;
    }
    d0 = blk_sum_1024(d0, sh);
    d1 = blk_sum_1024(d1, sh);
    d2 = blk_sum_1024(d2, sh);
    d3 = blk_sum_1024(d3, sh);
    float knorm = sqrtf(d0), krnorm = sqrtf(d1);

    float v[M_SLOTS / 1024];
    float mx = -INFINITY;
    #pragma unroll
    for (int j = 0; j < M_SLOTS / 1024; ++j) {
        int m = tid + j * 1024;
        v[j] = simk[m] / (sqrtf(n2old[m]) * knorm + EPS_F);
        mx = fmaxf(mx, v[j]);
    }
    mx = blk_max_1024(mx, sh);
    float ls = 0.f;
    #pragma unroll
    for (int j = 0; j < M_SLOTS / 1024; ++j) { v[j] = expf(v[j] - mx); ls += v[j]; }
    ls = blk_sum_1024(ls, sh);
    float inv = 1.f / ls;
    float wv[M_SLOTS / 1024];
    #pragma unroll
    for (int j = 0; j < M_SLOTS / 1024; ++j) {
        wv[j] = v[j] * inv;
        ww[tid + j * 1024] = wv[j];
    }

    float mx2 = -INFINITY;
    #pragma unroll
    for (int j = 0; j < M_SLOTS / 1024; ++j) {
        int m = tid + j * 1024;
        float w1 = wv[j];
        float sim2 = skr[m] - w1 * sekr[m] + w1 * d2;
        float n2 = n2old[m] - 2.f*w1*qe[m] + w1*w1*qe2[m]
                 + 2.f*w1*sa[m] - 2.f*w1*w1*sea[m] + w1*w1*d3;
        v[j] = sim2 / (sqrtf(n2) * krnorm + EPS_F);
        mx2 = fmaxf(mx2, v[j]);
    }
    mx2 = blk_max_1024(mx2, sh);
    float ls2 = 0.f;
    #pragma unroll
    for (int j = 0; j < M_SLOTS / 1024; ++j) { v[j] = expf(v[j] - mx2); ls2 += v[j]; }
    ls2 = blk_sum_1024(ls2, sh);
    float inv2 = 1.f / ls2;
    #pragma unroll
    for (int j = 0; j < M_SLOTS / 1024; ++j) wr[tid + j * 1024] = v[j] * inv2;
}

// Fused: mem_new = mem_old*(1-ww*e) + ww*a ; partial[rc] += wr*mem_new
// grid (4, NCHUNKS) x 256 threads; thread owns one float4 column, loops RCHUNK rows.
__global__ void k_update_read(const float* __restrict__ src, float* __restrict__ dst,
                              const float* __restrict__ ww, const float* __restrict__ wr,
                              const float* __restrict__ e, const float* __restrict__ a,
                              float* __restrict__ partial) {
    int c4 = blockIdx.x * 256 + threadIdx.x;   // [0, 1024)
    int rc = blockIdx.y;                       // [0, NCHUNKS)
    int r0 = rc * RCHUNK;
    const float4* s4 = (const float4*)src;
    float4*       d4 = (float4*)dst;
    float4 ee = ((const float4*)e)[c4];
    float4 aa = ((const float4*)a)[c4];
    float4 acc = make_float4(0.f, 0.f, 0.f, 0.f);
    #pragma unroll
    for (int r = r0; r < r0 + RCHUNK; ++r) {
        float w1 = ww[r], w2 = wr[r];
        float4 v = s4[(size_t)r * (N_DIM / 4) + c4];
        float4 nv;
        nv.x = v.x * (1.f - w1 * ee.x) + w1 * aa.x;
        nv.y = v.y * (1.f - w1 * ee.y) + w1 * aa.y;
        nv.z = v.z * (1.f - w1 * ee.z) + w1 * aa.z;
        nv.w = v.w * (1.f - w1 * ee.w) + w1 * aa.w;
        d4[(size_t)r * (N_DIM / 4) + c4] = nv;
        acc.x += w2 * nv.x; acc.y += w2 * nv.y; acc.z += w2 * nv.z; acc.w += w2 * nv.w;
    }
    ((float4*)partial)[(size_t)rc * (N_DIM / 4) + c4] = acc;
}

// red[c] = sum_j partial[j][c]   (16 blocks x 256)
__global__ void k_read_reduce(const float* __restrict__ partial, float* __restrict__ red) {
    int cidx = blockIdx.x * 256 + threadIdx.x;
    float acc = 0.f;
    #pragma unroll 8
    for (int j = 0; j < NCHUNKS; ++j) acc += partial[(size_t)j * N_DIM + cidx];
    red[cidx] = acc;
}

// X = tanh(X @ red.reshape(64,64)); optionally c = sigmoid(Wc@concat(X,prog)+bc)
__global__ void k_exec_ctrl(float* __restrict__ X, const float* __restrict__ red,
                            const float* __restrict__ prog_next,
                            const float* __restrict__ Wc, const float* __restrict__ bc,
                            float* __restrict__ c, int do_ctrl) {
    __shared__ float in[FVS + PLEN];
    __shared__ float xs[FVS];
    int tid = threadIdx.x;  // 256
    if (tid < FVS) xs[tid] = X[tid];
    __syncthreads();
    if (tid < FVS) {
        float acc = 0.f;
        #pragma unroll
        for (int i = 0; i < FVS; ++i) acc += xs[i] * red[i * FVS + tid];
        float xn = tanhf(acc);
        X[tid] = xn;
        in[tid] = xn;
    } else if (do_ctrl && tid < FVS + PLEN) {
        in[tid] = prog_next[tid - FVS];
    }
    __syncthreads();
    if (do_ctrl) {
        float acc = bc[tid];
        const float* wrow = Wc + tid * (FVS + PLEN);
        #pragma unroll 8
        for (int i = 0; i < FVS + PLEN; ++i) acc += wrow[i] * in[i];
        c[tid] = 1.f / (1.f + expf(-acc));
    }
}

// out = X @ output_embedding   (1x64 @ 64x512)
__global__ void k_out(const float* __restrict__ X, const float* __restrict__ emb,
                      float* __restrict__ out) {
    __shared__ float xs[FVS];
    int tid = threadIdx.x;  // 512
    if (tid < FVS) xs[tid] = X[tid];
    __syncthreads();
    float acc = 0.f;
    #pragma unroll
    for (int i = 0; i < FVS; ++i) acc += xs[i] * emb[i * NOUT + tid];
    out[tid] = acc;
}

// ---------------- launch ----------------

extern "C" void kernel_launch(void* const* d_in, const int* in_sizes, int n_in,
                              void* d_out, int out_size, void* d_ws, size_t ws_size,
                              hipStream_t stream) {
    const float* x        = (const float*)d_in[0];
    const float* program  = (const float*)d_in[1];
    const float* memory0  = (const float*)d_in[2];
    const float* in_emb   = (const float*)d_in[3];
    const float* out_emb  = (const float*)d_in[4];
    const float* Wc       = (const float*)d_in[5];
    const float* bc       = (const float*)d_in[6];
    const float* Wk       = (const float*)d_in[7];
    const float* bk       = (const float*)d_in[8];
    const float* We       = (const float*)d_in[9];
    const float* be       = (const float*)d_in[10];
    const float* Wa       = (const float*)d_in[11];
    const float* ba       = (const float*)d_in[12];
    const float* Wrk      = (const float*)d_in[13];
    const float* brk      = (const float*)d_in[14];
    float* out = (float*)d_out;

    float* wsmem   = (float*)d_ws;                        // [M_SLOTS * N_DIM]
    float* partial = wsmem + (size_t)M_SLOTS * N_DIM;     // [NCHUNKS * N_DIM]
    float* X       = partial + (size_t)NCHUNKS * N_DIM;
    float* c       = X + FVS;
    float* kv      = c + CDIM;
    float* ev      = kv + N_DIM;
    float* av      = ev + N_DIM;
    float* krv     = av + N_DIM;
    float* simk    = krv + N_DIM;
    float* n2old   = simk + M_SLOTS;
    float* skr     = n2old + M_SLOTS;
    float* sekr    = skr + M_SLOTS;
    float* sa      = sekr + M_SLOTS;
    float* sea     = sa + M_SLOTS;
    float* qe      = sea + M_SLOTS;
    float* qe2     = qe + M_SLOTS;
    float* ww      = qe2 + M_SLOTS;
    float* wr      = ww + M_SLOTS;
    float* red     = wr + M_SLOTS;

    k_init_ctrl<<<1, 256, 0, stream>>>(x, in_emb, program, Wc, bc, X, c);

    for (int t = 0; t < STEPS; ++t) {
        const float* prog_t = program + t * PLEN;
        const float* src    = (t == 0) ? memory0 : wsmem;

        k_keys<<<4096, 256, 0, stream>>>(c, prog_t, Wk, bk, We, be, Wa, ba, Wrk, brk,
                                         kv, ev, av, krv);
        k_sim8<<<M_SLOTS, 256, 0, stream>>>(
            src, kv, krv, av, ev, simk, n2old, skr, sekr, sa, sea, qe, qe2);
        k_addr<<<1, 1024, 0, stream>>>(kv, krv, av, simk, n2old, skr, sekr, sa, sea,
                                       qe, qe2, ww, wr);
        k_update_read<<<dim3(4, NCHUNKS), 256, 0, stream>>>(src, wsmem, ww, wr, ev, av, partial);
        k_read_reduce<<<16, 256, 0, stream>>>(partial, red);
        k_exec_ctrl<<<1, 256, 0, stream>>>(X, red,
                                           (t < STEPS - 1) ? program + (t + 1) * PLEN : nullptr,
                                           Wc, bc, c, (t < STEPS - 1) ? 1 : 0);
    }

    k_out<<<1, NOUT, 0, stream>>>(X, out_emb, out);
}